// Round 1
// baseline (826.291 us; speedup 1.0000x reference)
//
#include <hip/hip_runtime.h>

#define BATCH 8
#define CIN   64
#define COUT  64
#define HH    128
#define WW    128
#define OFFC  18
#define KK    9
#define PIX   16
#define SLD   580   // 576 + 4 pad (576 % 32 == 0 would be 16-way write conflict)

// ---------------- Kernel A: offsets = conv3x3(x, w_offset), pad 1 ----------------
__global__ __launch_bounds__(256) void offsets_conv_k(
    const float* __restrict__ x, const float* __restrict__ woff, float* __restrict__ offs)
{
    int idx = blockIdx.x * 256 + threadIdx.x;          // ((b*18+oc)*H+ho)*W+wo
    int wo = idx & (WW - 1);
    int ho = (idx >> 7) & (HH - 1);
    int t  = idx >> 14;
    int oc = t % OFFC;
    int b  = t / OFFC;
    const float* xb = x + (size_t)b * CIN * HH * WW;
    const float* wp = woff + oc * CIN * 9;
    float acc = 0.f;
    for (int c = 0; c < CIN; ++c) {
        const float* xc = xb + c * HH * WW;
        const float* wc = wp + c * 9;
        #pragma unroll
        for (int ky = 0; ky < 3; ++ky) {
            int y = ho + ky - 1;
            if ((unsigned)y >= HH) continue;
            const float* row = xc + y * WW;
            #pragma unroll
            for (int kx = 0; kx < 3; ++kx) {
                int xq = wo + kx - 1;
                if ((unsigned)xq >= WW) continue;
                acc = fmaf(row[xq], wc[ky * 3 + kx], acc);
            }
        }
    }
    offs[idx] = acc;
}

// ------------- Kernel B: w_deform (o,c,kh,kw) -> wT4[ck4][o][4], ck = k*64+c -------------
__global__ __launch_bounds__(256) void transpose_w_k(
    const float* __restrict__ wd, float* __restrict__ wT4)
{
    int idx = blockIdx.x * 256 + threadIdx.x;          // o*576 + c*9 + k
    int k = idx % 9;
    int c = (idx / 9) & 63;
    int o = idx / (CIN * 9);
    int ck = k * CIN + c;
    wT4[(ck >> 2) * (COUT * 4) + o * 4 + (ck & 3)] = wd[idx];
}

// ---------------- Kernel C: sample + GEMM ----------------
__global__ __launch_bounds__(256) void deform_main_k(
    const float* __restrict__ x, const float* __restrict__ offs,
    const float4* __restrict__ wT4, float* __restrict__ out)
{
    __shared__ float smp[PIX][SLD];      // sampled[pix][k*64+c]
    __shared__ float pos[PIX * KK][8];   // y0,x0,w00,w01,w10,w11 (reused as trans[64*17] later)

    int tid  = threadIdx.x;
    int blk  = blockIdx.x;               // b*1024 + ho*8 + wseg
    int wseg = blk & 7;
    int ho   = (blk >> 3) & (HH - 1);
    int b    = blk >> 10;
    int wo0  = wseg * PIX;

    // phase 0: positions + bilinear weights for 16 pixels x 9 taps
    if (tid < PIX * KK) {
        int p = tid / KK, k = tid % KK;
        int wo = wo0 + p;
        const float* ob = offs + (((size_t)b * OFFC + 2 * k) * HH + ho) * WW + wo;
        float dy = ob[0];
        float dx = ob[HH * WW];
        float yy = (float)(ho - 1 + k / 3) + dy;
        float xx = (float)(wo - 1 + k % 3) + dx;
        float y0 = floorf(yy), x0 = floorf(xx);
        float wy1 = yy - y0, wx1 = xx - x0;
        float wy0 = 1.f - wy1, wx0 = 1.f - wx1;
        bool valid = (yy > -1.f) && (yy < (float)HH) && (xx > -1.f) && (xx < (float)WW);
        float m = valid ? 1.f : 0.f;
        pos[tid][0] = y0;
        pos[tid][1] = x0;
        pos[tid][2] = wy0 * wx0 * m;
        pos[tid][3] = wy0 * wx1 * m;
        pos[tid][4] = wy1 * wx0 * m;
        pos[tid][5] = wy1 * wx1 * m;
    }
    __syncthreads();

    // phase 1: gather 16 pix x 9 k x 64 c into LDS (thread: pix=tid&15, csub=tid>>4)
    int pix  = tid & 15;
    int csub = tid >> 4;
    const float* xb = x + (size_t)b * CIN * HH * WW;
    for (int k = 0; k < KK; ++k) {
        const float* pp = pos[pix * KK + k];
        float y0f = pp[0], x0f = pp[1];
        float w00 = pp[2], w01 = pp[3], w10 = pp[4], w11 = pp[5];
        int y0i = (int)y0f, x0i = (int)x0f;
        #pragma unroll
        for (int cc = 0; cc < 4; ++cc) {
            int c = csub + cc * 16;
            const float* xc = xb + c * HH * WW;
            float v = 0.f;
            if ((unsigned)y0i < HH) {
                const float* r = xc + y0i * WW;
                if ((unsigned)x0i < WW)       v = fmaf(w00, r[x0i], v);
                if ((unsigned)(x0i + 1) < WW) v = fmaf(w01, r[x0i + 1], v);
            }
            if ((unsigned)(y0i + 1) < HH) {
                const float* r = xc + (y0i + 1) * WW;
                if ((unsigned)x0i < WW)       v = fmaf(w10, r[x0i], v);
                if ((unsigned)(x0i + 1) < WW) v = fmaf(w11, r[x0i + 1], v);
            }
            smp[pix][k * CIN + c] = v;
        }
    }
    __syncthreads();

    // phase 2: out[pix][o] = sum_ck smp[pix][ck] * w[o][ck]; thread: o=tid&63, 4 pixels
    int o = tid & 63;
    int q = tid >> 6;
    const float4* s0 = (const float4*)(&smp[q * 4 + 0][0]);
    const float4* s1 = (const float4*)(&smp[q * 4 + 1][0]);
    const float4* s2 = (const float4*)(&smp[q * 4 + 2][0]);
    const float4* s3 = (const float4*)(&smp[q * 4 + 3][0]);
    float a0 = 0.f, a1 = 0.f, a2 = 0.f, a3 = 0.f;
    #pragma unroll 4
    for (int ck4 = 0; ck4 < 144; ++ck4) {
        float4 wv = wT4[ck4 * 64 + o];
        float4 v0 = s0[ck4], v1 = s1[ck4], v2 = s2[ck4], v3 = s3[ck4];
        a0 += wv.x * v0.x + wv.y * v0.y + wv.z * v0.z + wv.w * v0.w;
        a1 += wv.x * v1.x + wv.y * v1.y + wv.z * v1.z + wv.w * v1.w;
        a2 += wv.x * v2.x + wv.y * v2.y + wv.z * v2.z + wv.w * v2.w;
        a3 += wv.x * v3.x + wv.y * v3.y + wv.z * v3.z + wv.w * v3.w;
    }
    __syncthreads();

    // epilogue: transpose through LDS (stride 17 to avoid bank conflicts) for coalesced stores
    float* trans = &pos[0][0];           // 4608 B >= 64*17*4 = 4352 B
    trans[o * 17 + q * 4 + 0] = a0;
    trans[o * 17 + q * 4 + 1] = a1;
    trans[o * 17 + q * 4 + 2] = a2;
    trans[o * 17 + q * 4 + 3] = a3;
    __syncthreads();

    int col = tid & 15;
    int og  = tid >> 4;                  // 0..15
    #pragma unroll
    for (int j = 0; j < 4; ++j) {
        int oo = og + j * 16;
        out[(((size_t)b * COUT + oo) * HH + ho) * WW + wo0 + col] = trans[oo * 17 + col];
    }
}

extern "C" void kernel_launch(void* const* d_in, const int* in_sizes, int n_in,
                              void* d_out, int out_size, void* d_ws, size_t ws_size,
                              hipStream_t stream)
{
    const float* x    = (const float*)d_in[0];
    const float* woff = (const float*)d_in[1];
    const float* wdef = (const float*)d_in[2];
    float* out  = (float*)d_out;
    float* offs = (float*)d_ws;                                    // 8*18*128*128 f32 = 9.44 MB
    float* wT4  = offs + (size_t)BATCH * OFFC * HH * WW;           // 576*64 f32 = 147 KB

    hipLaunchKernelGGL(offsets_conv_k, dim3(BATCH * OFFC * HH * WW / 256), dim3(256), 0, stream,
                       x, woff, offs);
    hipLaunchKernelGGL(transpose_w_k, dim3(COUT * CIN * 9 / 256), dim3(256), 0, stream,
                       wdef, wT4);
    hipLaunchKernelGGL(deform_main_k, dim3(BATCH * HH * (WW / PIX)), dim3(256), 0, stream,
                       x, offs, (const float4*)wT4, out);
}

// Round 2
// 540.557 us; speedup vs baseline: 1.5286x; 1.5286x over previous
//
#include <hip/hip_runtime.h>

#define BATCH 8
#define CIN   64
#define COUT  64
#define HH    128
#define WW    128
#define OFFC  18
#define KK    9
#define PIX   16
#define SLD   580   // 576 + 4 pad (576 % 32 == 0 would be 16-way write conflict)

// ---------------- Kernel A: offsets = conv3x3(x, w_offset), pad 1 ----------------
// Block = 16x16 output tile, 1 pixel/thread, all 18 oc in registers.
// Per input channel: 18x18 halo tile staged in LDS, double-buffered with
// register prefetch. Weights via wave-uniform (scalar) loads from global.
__global__ __launch_bounds__(256) void offsets_conv_k(
    const float* __restrict__ x, const float* __restrict__ woff, float* __restrict__ offs)
{
    __shared__ float xt[2][18 * 18];

    int tid = threadIdx.x;
    int blk = blockIdx.x;                  // b*64 + tyi*8 + txi
    int txi = blk & 7;
    int tyi = (blk >> 3) & 7;
    int b   = blk >> 6;
    int ty0 = tyi * 16, tx0 = txi * 16;
    int tx = tid & 15, ty = tid >> 4;

    const float* xb = x + (size_t)b * CIN * HH * WW;

    // halo-load coordinates (loop-invariant): element i0 = tid, i1 = tid+256
    int i0 = tid, i1 = tid + 256;
    int gy0 = ty0 - 1 + i0 / 18, gx0 = tx0 - 1 + i0 % 18;
    int gy1 = ty0 - 1 + i1 / 18, gx1 = tx0 - 1 + i1 % 18;
    bool v0 = (unsigned)gy0 < HH && (unsigned)gx0 < WW;
    bool v1 = (i1 < 324) && (unsigned)gy1 < HH && (unsigned)gx1 < WW;
    int off0 = gy0 * WW + gx0;
    int off1 = gy1 * WW + gx1;

    float acc[OFFC];
    #pragma unroll
    for (int i = 0; i < OFFC; ++i) acc[i] = 0.f;

    // prefetch channel 0
    float r0 = v0 ? xb[off0] : 0.f;
    float r1 = v1 ? xb[off1] : 0.f;
    xt[0][i0] = r0;
    if (i1 < 324) xt[0][i1] = r1;

    for (int c = 0; c < CIN; ++c) {
        // issue next channel's loads early (hide under compute)
        if (c + 1 < CIN) {
            const float* xc = xb + (size_t)(c + 1) * HH * WW;
            r0 = v0 ? xc[off0] : 0.f;
            r1 = v1 ? xc[off1] : 0.f;
        }
        __syncthreads();                    // xt[c&1] fully written

        const float* cur = xt[c & 1];
        float xr[9];
        #pragma unroll
        for (int r = 0; r < 3; ++r)
            #pragma unroll
            for (int s = 0; s < 3; ++s)
                xr[r * 3 + s] = cur[(ty + r) * 18 + (tx + s)];

        const float* wc = woff + c * 9;     // w[oc][c][k] at wc + oc*576 + k (uniform -> s_load)
        #pragma unroll
        for (int oc = 0; oc < OFFC; ++oc) {
            const float* wp = wc + oc * (CIN * 9);
            #pragma unroll
            for (int k = 0; k < 9; ++k)
                acc[oc] = fmaf(xr[k], wp[k], acc[oc]);
        }

        // write next buffer (readers of it sync at next iteration's barrier)
        if (c + 1 < CIN) {
            xt[(c + 1) & 1][i0] = r0;
            if (i1 < 324) xt[(c + 1) & 1][i1] = r1;
        }
    }

    int ho = ty0 + ty, wo = tx0 + tx;
    #pragma unroll
    for (int oc = 0; oc < OFFC; ++oc)
        offs[(((size_t)b * OFFC + oc) * HH + ho) * WW + wo] = acc[oc];
}

// ------------- Kernel B: w_deform (o,c,kh,kw) -> wT4[ck4][o][4], ck = k*64+c -------------
__global__ __launch_bounds__(256) void transpose_w_k(
    const float* __restrict__ wd, float* __restrict__ wT4)
{
    int idx = blockIdx.x * 256 + threadIdx.x;          // o*576 + c*9 + k
    int k = idx % 9;
    int c = (idx / 9) & 63;
    int o = idx / (CIN * 9);
    int ck = k * CIN + c;
    wT4[(ck >> 2) * (COUT * 4) + o * 4 + (ck & 3)] = wd[idx];
}

// ---------------- Kernel C: sample + GEMM ----------------
__global__ __launch_bounds__(256) void deform_main_k(
    const float* __restrict__ x, const float* __restrict__ offs,
    const float4* __restrict__ wT4, float* __restrict__ out)
{
    __shared__ float smp[PIX][SLD];      // sampled[pix][k*64+c]
    __shared__ float pos[PIX * KK][8];   // y0,x0,w00,w01,w10,w11 (reused as trans[64*17] later)

    int tid  = threadIdx.x;
    int blk  = blockIdx.x;               // b*1024 + ho*8 + wseg
    int wseg = blk & 7;
    int ho   = (blk >> 3) & (HH - 1);
    int b    = blk >> 10;
    int wo0  = wseg * PIX;

    // phase 0: positions + bilinear weights for 16 pixels x 9 taps
    if (tid < PIX * KK) {
        int p = tid / KK, k = tid % KK;
        int wo = wo0 + p;
        const float* ob = offs + (((size_t)b * OFFC + 2 * k) * HH + ho) * WW + wo;
        float dy = ob[0];
        float dx = ob[HH * WW];
        float yy = (float)(ho - 1 + k / 3) + dy;
        float xx = (float)(wo - 1 + k % 3) + dx;
        float y0 = floorf(yy), x0 = floorf(xx);
        float wy1 = yy - y0, wx1 = xx - x0;
        float wy0 = 1.f - wy1, wx0 = 1.f - wx1;
        bool valid = (yy > -1.f) && (yy < (float)HH) && (xx > -1.f) && (xx < (float)WW);
        float m = valid ? 1.f : 0.f;
        pos[tid][0] = y0;
        pos[tid][1] = x0;
        pos[tid][2] = wy0 * wx0 * m;
        pos[tid][3] = wy0 * wx1 * m;
        pos[tid][4] = wy1 * wx0 * m;
        pos[tid][5] = wy1 * wx1 * m;
    }
    __syncthreads();

    // phase 1: gather 16 pix x 9 k x 64 c into LDS (thread: pix=tid&15, csub=tid>>4)
    int pix  = tid & 15;
    int csub = tid >> 4;
    const float* xb = x + (size_t)b * CIN * HH * WW;
    for (int k = 0; k < KK; ++k) {
        const float* pp = pos[pix * KK + k];
        float y0f = pp[0], x0f = pp[1];
        float w00 = pp[2], w01 = pp[3], w10 = pp[4], w11 = pp[5];
        int y0i = (int)y0f, x0i = (int)x0f;
        #pragma unroll
        for (int cc = 0; cc < 4; ++cc) {
            int c = csub + cc * 16;
            const float* xc = xb + c * HH * WW;
            float v = 0.f;
            if ((unsigned)y0i < HH) {
                const float* r = xc + y0i * WW;
                if ((unsigned)x0i < WW)       v = fmaf(w00, r[x0i], v);
                if ((unsigned)(x0i + 1) < WW) v = fmaf(w01, r[x0i + 1], v);
            }
            if ((unsigned)(y0i + 1) < HH) {
                const float* r = xc + (y0i + 1) * WW;
                if ((unsigned)x0i < WW)       v = fmaf(w10, r[x0i], v);
                if ((unsigned)(x0i + 1) < WW) v = fmaf(w11, r[x0i + 1], v);
            }
            smp[pix][k * CIN + c] = v;
        }
    }
    __syncthreads();

    // phase 2: out[pix][o] = sum_ck smp[pix][ck] * w[o][ck]; thread: o=tid&63, 4 pixels
    int o = tid & 63;
    int q = tid >> 6;
    const float4* s0 = (const float4*)(&smp[q * 4 + 0][0]);
    const float4* s1 = (const float4*)(&smp[q * 4 + 1][0]);
    const float4* s2 = (const float4*)(&smp[q * 4 + 2][0]);
    const float4* s3 = (const float4*)(&smp[q * 4 + 3][0]);
    float a0 = 0.f, a1 = 0.f, a2 = 0.f, a3 = 0.f;
    #pragma unroll 4
    for (int ck4 = 0; ck4 < 144; ++ck4) {
        float4 wv = wT4[ck4 * 64 + o];
        float4 v0 = s0[ck4], v1 = s1[ck4], v2 = s2[ck4], v3 = s3[ck4];
        a0 += wv.x * v0.x + wv.y * v0.y + wv.z * v0.z + wv.w * v0.w;
        a1 += wv.x * v1.x + wv.y * v1.y + wv.z * v1.z + wv.w * v1.w;
        a2 += wv.x * v2.x + wv.y * v2.y + wv.z * v2.z + wv.w * v2.w;
        a3 += wv.x * v3.x + wv.y * v3.y + wv.z * v3.z + wv.w * v3.w;
    }
    __syncthreads();

    // epilogue: transpose through LDS (stride 17 to avoid bank conflicts) for coalesced stores
    float* trans = &pos[0][0];           // 4608 B >= 64*17*4 = 4352 B
    trans[o * 17 + q * 4 + 0] = a0;
    trans[o * 17 + q * 4 + 1] = a1;
    trans[o * 17 + q * 4 + 2] = a2;
    trans[o * 17 + q * 4 + 3] = a3;
    __syncthreads();

    int col = tid & 15;
    int og  = tid >> 4;                  // 0..15
    #pragma unroll
    for (int j = 0; j < 4; ++j) {
        int oo = og + j * 16;
        out[(((size_t)b * COUT + oo) * HH + ho) * WW + wo0 + col] = trans[oo * 17 + col];
    }
}

extern "C" void kernel_launch(void* const* d_in, const int* in_sizes, int n_in,
                              void* d_out, int out_size, void* d_ws, size_t ws_size,
                              hipStream_t stream)
{
    const float* x    = (const float*)d_in[0];
    const float* woff = (const float*)d_in[1];
    const float* wdef = (const float*)d_in[2];
    float* out  = (float*)d_out;
    float* offs = (float*)d_ws;                                    // 8*18*128*128 f32 = 9.44 MB
    float* wT4  = offs + (size_t)BATCH * OFFC * HH * WW;           // 576*64 f32 = 147 KB

    hipLaunchKernelGGL(offsets_conv_k, dim3(BATCH * 64), dim3(256), 0, stream,
                       x, woff, offs);
    hipLaunchKernelGGL(transpose_w_k, dim3(COUT * CIN * 9 / 256), dim3(256), 0, stream,
                       wdef, wT4);
    hipLaunchKernelGGL(deform_main_k, dim3(BATCH * HH * (WW / PIX)), dim3(256), 0, stream,
                       x, offs, (const float4*)wT4, out);
}

// Round 3
// 361.973 us; speedup vs baseline: 2.2827x; 1.4934x over previous
//
#include <hip/hip_runtime.h>
#include <hip/hip_bf16.h>

#define BATCH 8
#define CIN   64
#define COUT  64
#define HH    128
#define WW    128
#define HW    (HH * WW)
#define OFFC  18
#define KK    9

typedef __attribute__((ext_vector_type(8))) short short8;
typedef __attribute__((ext_vector_type(4))) float f32x4;

// ---------------- Kernel A: offsets = conv3x3(x, w_offset), pad 1 ----------------
// 16x16 tile/block, 18 oc in registers, LDS halo double-buffered.
__global__ __launch_bounds__(256) void offsets_conv_k(
    const float* __restrict__ x, const float* __restrict__ woff, float* __restrict__ offs)
{
    __shared__ float xt[2][18 * 18];

    int tid = threadIdx.x;
    int blk = blockIdx.x;                  // b*64 + tyi*8 + txi
    int txi = blk & 7;
    int tyi = (blk >> 3) & 7;
    int b   = blk >> 6;
    int ty0 = tyi * 16, tx0 = txi * 16;
    int tx = tid & 15, ty = tid >> 4;

    const float* xb = x + (size_t)b * CIN * HW;

    int i0 = tid, i1 = tid + 256;
    int gy0 = ty0 - 1 + i0 / 18, gx0 = tx0 - 1 + i0 % 18;
    int gy1 = ty0 - 1 + i1 / 18, gx1 = tx0 - 1 + i1 % 18;
    bool v0 = (unsigned)gy0 < HH && (unsigned)gx0 < WW;
    bool v1 = (i1 < 324) && (unsigned)gy1 < HH && (unsigned)gx1 < WW;
    int off0 = gy0 * WW + gx0;
    int off1 = gy1 * WW + gx1;

    float acc[OFFC];
    #pragma unroll
    for (int i = 0; i < OFFC; ++i) acc[i] = 0.f;

    float r0 = v0 ? xb[off0] : 0.f;
    float r1 = v1 ? xb[off1] : 0.f;
    xt[0][i0] = r0;
    if (i1 < 324) xt[0][i1] = r1;

    for (int c = 0; c < CIN; ++c) {
        if (c + 1 < CIN) {
            const float* xc = xb + (size_t)(c + 1) * HW;
            r0 = v0 ? xc[off0] : 0.f;
            r1 = v1 ? xc[off1] : 0.f;
        }
        __syncthreads();

        const float* cur = xt[c & 1];
        float xr[9];
        #pragma unroll
        for (int r = 0; r < 3; ++r)
            #pragma unroll
            for (int s = 0; s < 3; ++s)
                xr[r * 3 + s] = cur[(ty + r) * 18 + (tx + s)];

        const float* wc = woff + c * 9;
        #pragma unroll
        for (int oc = 0; oc < OFFC; ++oc) {
            const float* wp = wc + oc * (CIN * 9);
            #pragma unroll
            for (int k = 0; k < 9; ++k)
                acc[oc] = fmaf(xr[k], wp[k], acc[oc]);
        }

        if (c + 1 < CIN) {
            xt[(c + 1) & 1][i0] = r0;
            if (i1 < 324) xt[(c + 1) & 1][i1] = r1;
        }
    }

    int ho = ty0 + ty, wo = tx0 + tx;
    #pragma unroll
    for (int oc = 0; oc < OFFC; ++oc)
        offs[(((size_t)b * OFFC + oc) * HH + ho) * WW + wo] = acc[oc];
}

// ------- Kernel B: w_deform (o,c,kh,kw) -> bf16 B-fragments wf[kk][nt][lane][8] -------
// B[k=kk*32+(lane>>4)*8+j][col=lane&15] = w[o=nt*16+col][ck=k], ck = tap*64+c
__global__ __launch_bounds__(256) void build_wfrag_k(
    const float* __restrict__ wd, unsigned short* __restrict__ wf)
{
    int idx = blockIdx.x * 256 + threadIdx.x;   // o*576 + ck, 36864 total
    int ck = idx % 576;
    int o  = idx / 576;
    int c = ck & 63, k = ck >> 6;
    float v = wd[o * 576 + c * 9 + k];
    int kk = ck >> 5, nt = o >> 4;
    int lane = (o & 15) | (((ck >> 3) & 3) << 4);
    int j = ck & 7;
    __hip_bfloat16 h = __float2bfloat16(v);
    wf[((kk * 4 + nt) * 64 + lane) * 8 + j] = *reinterpret_cast<unsigned short*>(&h);
}

// ---------------- Kernel C: gather-to-fragment + MFMA ----------------
// Block = 64 pixels (one half-row) x 64 outputs. 4 waves, wave w owns pixels w*16..+15.
// K-loop: 18 steps of 32 ck; lane l gathers 8 channels of one bilinear sample directly
// into its A-fragment (no sample LDS). B-fragments from pre-packed global (L2-hot).
__global__ __launch_bounds__(256) void deform_main_k(
    const float* __restrict__ x, const float* __restrict__ offs,
    const short8* __restrict__ wf, float* __restrict__ out)
{
    __shared__ alignas(16) char smem[576 * 32];   // posI[576]+posW[576]; reused as trans[64*65]f32
    int4*   posI  = (int4*)smem;
    float4* posW  = (float4*)(smem + 576 * 16);
    float*  trans = (float*)smem;

    int tid  = threadIdx.x;
    int blk  = blockIdx.x;               // b*256 + ho*2 + wseg
    int wseg = blk & 1;
    int ho   = (blk >> 1) & (HH - 1);
    int b    = blk >> 8;
    int wo0  = wseg * 64;

    const float* xb = x + (size_t)b * CIN * HW;

    // phase 0: 64 pixels x 9 taps -> clamped corner offsets + pre-masked bilinear weights
    for (int e = tid; e < 576; e += 256) {
        int p = e / 9, k = e - p * 9;
        int wo = wo0 + p;
        float dy = offs[(((size_t)b * OFFC + 2 * k) * HH + ho) * WW + wo];
        float dx = offs[(((size_t)b * OFFC + 2 * k + 1) * HH + ho) * WW + wo];
        float yy = (float)(ho - 1 + k / 3) + dy;
        float xx = (float)(wo - 1 + k % 3) + dx;
        float y0 = floorf(yy), x0 = floorf(xx);
        float wy1 = yy - y0, wx1 = xx - x0;
        float wy0 = 1.f - wy1, wx0 = 1.f - wx1;
        bool valid = (yy > -1.f) && (yy < (float)HH) && (xx > -1.f) && (xx < (float)WW);
        int y0i = (int)y0, x0i = (int)x0;
        bool iy0 = (unsigned)y0i < HH, iy1 = (unsigned)(y0i + 1) < HH;
        bool ix0 = (unsigned)x0i < WW, ix1 = (unsigned)(x0i + 1) < WW;
        float m00 = (valid && iy0 && ix0) ? 1.f : 0.f;
        float m01 = (valid && iy0 && ix1) ? 1.f : 0.f;
        float m10 = (valid && iy1 && ix0) ? 1.f : 0.f;
        float m11 = (valid && iy1 && ix1) ? 1.f : 0.f;
        int yc0 = min(max(y0i, 0), HH - 1), yc1 = min(max(y0i + 1, 0), HH - 1);
        int xc0 = min(max(x0i, 0), WW - 1), xc1 = min(max(x0i + 1, 0), WW - 1);
        posI[e] = make_int4(yc0 * WW + xc0, yc0 * WW + xc1, yc1 * WW + xc0, yc1 * WW + xc1);
        posW[e] = make_float4(wy0 * wx0 * m00, wy0 * wx1 * m01, wy1 * wx0 * m10, wy1 * wx1 * m11);
    }
    __syncthreads();

    int lane  = tid & 63;
    int wave  = tid >> 6;
    int prow  = lane & 15;               // A row within wave tile
    int khalf = lane >> 4;               // 0..3 -> k-subchunk
    int ebase = (wave * 16 + prow) * 9;

    f32x4 acc0 = {0.f, 0.f, 0.f, 0.f};
    f32x4 acc1 = {0.f, 0.f, 0.f, 0.f};
    f32x4 acc2 = {0.f, 0.f, 0.f, 0.f};
    f32x4 acc3 = {0.f, 0.f, 0.f, 0.f};

    #pragma unroll 2
    for (int kk = 0; kk < 18; ++kk) {
        int tap = kk >> 1;
        short8 bf0 = wf[(kk * 4 + 0) * 64 + lane];
        short8 bf1 = wf[(kk * 4 + 1) * 64 + lane];
        short8 bf2 = wf[(kk * 4 + 2) * 64 + lane];
        short8 bf3 = wf[(kk * 4 + 3) * 64 + lane];
        int4   io = posI[ebase + tap];
        float4 w4 = posW[ebase + tap];
        int c0 = ((kk & 1) << 5) + (khalf << 3);
        const float* basep = xb + (size_t)c0 * HW;
        short8 a;
        #pragma unroll
        for (int j = 0; j < 8; ++j) {
            const float* xc = basep + (size_t)j * HW;
            float v = w4.x * xc[io.x] + w4.y * xc[io.y] + w4.z * xc[io.z] + w4.w * xc[io.w];
            __hip_bfloat16 h = __float2bfloat16(v);
            a[j] = *reinterpret_cast<short*>(&h);
        }
        acc0 = __builtin_amdgcn_mfma_f32_16x16x32_bf16(a, bf0, acc0, 0, 0, 0);
        acc1 = __builtin_amdgcn_mfma_f32_16x16x32_bf16(a, bf1, acc1, 0, 0, 0);
        acc2 = __builtin_amdgcn_mfma_f32_16x16x32_bf16(a, bf2, acc2, 0, 0, 0);
        acc3 = __builtin_amdgcn_mfma_f32_16x16x32_bf16(a, bf3, acc3, 0, 0, 0);
    }
    __syncthreads();                     // pos arrays dead; reuse as trans

    // D layout: col=lane&15 (o within tile), row=(lane>>4)*4+reg (pixel within wave)
    int ocol = lane & 15;
    int pr   = wave * 16 + khalf * 4;
    #pragma unroll
    for (int r = 0; r < 4; ++r) {
        trans[(0 * 16 + ocol) * 65 + pr + r] = acc0[r];
        trans[(1 * 16 + ocol) * 65 + pr + r] = acc1[r];
        trans[(2 * 16 + ocol) * 65 + pr + r] = acc2[r];
        trans[(3 * 16 + ocol) * 65 + pr + r] = acc3[r];
    }
    __syncthreads();

    float* ob = out + ((size_t)b * COUT * HH + ho) * WW + wo0;
    for (int i = tid; i < 64 * 64; i += 256) {
        int o = i >> 6, w = i & 63;
        ob[(size_t)o * HW + w] = trans[o * 65 + w];
    }
}

extern "C" void kernel_launch(void* const* d_in, const int* in_sizes, int n_in,
                              void* d_out, int out_size, void* d_ws, size_t ws_size,
                              hipStream_t stream)
{
    const float* x    = (const float*)d_in[0];
    const float* woff = (const float*)d_in[1];
    const float* wdef = (const float*)d_in[2];
    float* out  = (float*)d_out;
    float* offs = (float*)d_ws;                                    // 9.44 MB
    unsigned short* wfrag = (unsigned short*)(offs + (size_t)BATCH * OFFC * HW);  // 73.7 KB

    hipLaunchKernelGGL(offsets_conv_k, dim3(BATCH * 64), dim3(256), 0, stream,
                       x, woff, offs);
    hipLaunchKernelGGL(build_wfrag_k, dim3(COUT * 576 / 256), dim3(256), 0, stream,
                       wdef, wfrag);
    hipLaunchKernelGGL(deform_main_k, dim3(BATCH * HH * 2), dim3(256), 0, stream,
                       x, offs, (const short8*)wfrag, out);
}

// Round 4
// 247.691 us; speedup vs baseline: 3.3360x; 1.4614x over previous
//
#include <hip/hip_runtime.h>
#include <hip/hip_bf16.h>

#define BATCH 8
#define CIN   64
#define COUT  64
#define HH    128
#define WW    128
#define HW    (HH * WW)
#define OFFC  18
#define KK    9

typedef __attribute__((ext_vector_type(8))) short short8;
typedef __attribute__((ext_vector_type(8))) unsigned short ushort8;
typedef __attribute__((ext_vector_type(4))) float f32x4;

__device__ __forceinline__ float bf2f(unsigned short u) {
    return __builtin_bit_cast(float, ((unsigned int)u) << 16);
}
__device__ __forceinline__ short f2bf(float v) {
    __hip_bfloat16 h = __float2bfloat16(v);
    return __builtin_bit_cast(short, h);
}

// ---------------- Kernel A: offsets = conv3x3(x, w_offset), pad 1 ----------------
// 16x16 tile/block, 18 oc in registers, LDS halo double-buffered.
__global__ __launch_bounds__(256) void offsets_conv_k(
    const float* __restrict__ x, const float* __restrict__ woff, float* __restrict__ offs)
{
    __shared__ float xt[2][18 * 18];

    int tid = threadIdx.x;
    int blk = blockIdx.x;                  // b*64 + tyi*8 + txi
    int txi = blk & 7;
    int tyi = (blk >> 3) & 7;
    int b   = blk >> 6;
    int ty0 = tyi * 16, tx0 = txi * 16;
    int tx = tid & 15, ty = tid >> 4;

    const float* xb = x + (size_t)b * CIN * HW;

    int i0 = tid, i1 = tid + 256;
    int gy0 = ty0 - 1 + i0 / 18, gx0 = tx0 - 1 + i0 % 18;
    int gy1 = ty0 - 1 + i1 / 18, gx1 = tx0 - 1 + i1 % 18;
    bool v0 = (unsigned)gy0 < HH && (unsigned)gx0 < WW;
    bool v1 = (i1 < 324) && (unsigned)gy1 < HH && (unsigned)gx1 < WW;
    int off0 = gy0 * WW + gx0;
    int off1 = gy1 * WW + gx1;

    float acc[OFFC];
    #pragma unroll
    for (int i = 0; i < OFFC; ++i) acc[i] = 0.f;

    float r0 = v0 ? xb[off0] : 0.f;
    float r1 = v1 ? xb[off1] : 0.f;
    xt[0][i0] = r0;
    if (i1 < 324) xt[0][i1] = r1;

    for (int c = 0; c < CIN; ++c) {
        if (c + 1 < CIN) {
            const float* xc = xb + (size_t)(c + 1) * HW;
            r0 = v0 ? xc[off0] : 0.f;
            r1 = v1 ? xc[off1] : 0.f;
        }
        __syncthreads();

        const float* cur = xt[c & 1];
        float xr[9];
        #pragma unroll
        for (int r = 0; r < 3; ++r)
            #pragma unroll
            for (int s = 0; s < 3; ++s)
                xr[r * 3 + s] = cur[(ty + r) * 18 + (tx + s)];

        const float* wc = woff + c * 9;
        #pragma unroll
        for (int oc = 0; oc < OFFC; ++oc) {
            const float* wp = wc + oc * (CIN * 9);
            #pragma unroll
            for (int k = 0; k < 9; ++k)
                acc[oc] = fmaf(xr[k], wp[k], acc[oc]);
        }

        if (c + 1 < CIN) {
            xt[(c + 1) & 1][i0] = r0;
            if (i1 < 324) xt[(c + 1) & 1][i1] = r1;
        }
    }

    int ho = ty0 + ty, wo = tx0 + tx;
    #pragma unroll
    for (int oc = 0; oc < OFFC; ++oc)
        offs[(((size_t)b * OFFC + oc) * HH + ho) * WW + wo] = acc[oc];
}

// ------- Kernel X: x (b,c,h,w) f32 -> xT (b,h,w,c) bf16, one (b,ho) row per block -------
__global__ __launch_bounds__(256) void to_chlast_k(
    const float* __restrict__ x, unsigned short* __restrict__ xT)
{
    __shared__ unsigned short t[128 * 72];   // [w][c], pad 72 keeps 16B-aligned ushort8 rows
    int blk = blockIdx.x;                    // b*HH + ho
    int ho = blk & (HH - 1);
    int b  = blk >> 7;
    int tid = threadIdx.x;

    const float* xr = x + (size_t)b * CIN * HW + ho * WW;
    for (int i = tid; i < 2048; i += 256) {  // c = i>>5, 4 consecutive w
        int c = i >> 5, w4 = (i & 31) * 4;
        float4 v = *(const float4*)(xr + (size_t)c * HW + w4);
        t[(w4 + 0) * 72 + c] = (unsigned short)f2bf(v.x);
        t[(w4 + 1) * 72 + c] = (unsigned short)f2bf(v.y);
        t[(w4 + 2) * 72 + c] = (unsigned short)f2bf(v.z);
        t[(w4 + 3) * 72 + c] = (unsigned short)f2bf(v.w);
    }
    __syncthreads();

    unsigned short* orow = xT + (size_t)blk * WW * 64;
    for (int j = tid; j < 1024; j += 256) {  // w = j>>3, 8 channels
        int w = j >> 3, c8 = (j & 7) * 8;
        *(ushort8*)(orow + w * 64 + c8) = *(const ushort8*)(t + w * 72 + c8);
    }
}

// ------- Kernel B: w_deform (o,c,kh,kw) -> bf16 B-fragments wf[kk][nt][lane][8] -------
// B[k=kk*32+(lane>>4)*8+j][col=lane&15] = w[o=nt*16+col][ck=k], ck = tap*64+c
__global__ __launch_bounds__(256) void build_wfrag_k(
    const float* __restrict__ wd, unsigned short* __restrict__ wf)
{
    int idx = blockIdx.x * 256 + threadIdx.x;   // o*576 + ck, 36864 total
    int ck = idx % 576;
    int o  = idx / 576;
    int c = ck & 63, k = ck >> 6;
    float v = wd[o * 576 + c * 9 + k];
    int kk = ck >> 5, nt = o >> 4;
    int lane = (o & 15) | (((ck >> 3) & 3) << 4);
    int j = ck & 7;
    wf[((kk * 4 + nt) * 64 + lane) * 8 + j] = (unsigned short)f2bf(v);
}

// ---------------- Kernel C: gather-to-fragment + MFMA ----------------
// Block = 64 pixels (half-row) x 64 outputs. Gather from channels-last bf16 xT:
// lane reads 4 corners x 8 consecutive channels as 16B vector loads.
// Grid encoded blk = (ho*2+wseg)*8 + b so each XCD (round-robin blk%8) owns one batch
// -> per-XCD working set (2.1MB xT + 1.2MB offs) fits the 4MB XCD L2.
__global__ __launch_bounds__(256) void deform_main_k(
    const unsigned short* __restrict__ xT, const float* __restrict__ offs,
    const short8* __restrict__ wf, float* __restrict__ out)
{
    __shared__ alignas(16) char smem[576 * 32];   // posI[576]+posW[576]; reused as trans[64*65]f32
    int4*   posI  = (int4*)smem;
    float4* posW  = (float4*)(smem + 576 * 16);
    float*  trans = (float*)smem;

    int tid  = threadIdx.x;
    int blk  = blockIdx.x;               // (ho*2+wseg)*8 + b
    int b    = blk & 7;
    int t    = blk >> 3;
    int wseg = t & 1;
    int ho   = t >> 1;
    int wo0  = wseg * 64;

    const unsigned short* pT = xT + (size_t)b * HW * 64;

    // phase 0: 64 pixels x 9 taps -> clamped corner pixel-indices + pre-masked weights
    for (int e = tid; e < 576; e += 256) {
        int p = e / 9, k = e - p * 9;
        int wo = wo0 + p;
        float dy = offs[(((size_t)b * OFFC + 2 * k) * HH + ho) * WW + wo];
        float dx = offs[(((size_t)b * OFFC + 2 * k + 1) * HH + ho) * WW + wo];
        float yy = (float)(ho - 1 + k / 3) + dy;
        float xx = (float)(wo - 1 + k % 3) + dx;
        float y0 = floorf(yy), x0 = floorf(xx);
        float wy1 = yy - y0, wx1 = xx - x0;
        float wy0 = 1.f - wy1, wx0 = 1.f - wx1;
        bool valid = (yy > -1.f) && (yy < (float)HH) && (xx > -1.f) && (xx < (float)WW);
        int y0i = (int)y0, x0i = (int)x0;
        bool iy0 = (unsigned)y0i < HH, iy1 = (unsigned)(y0i + 1) < HH;
        bool ix0 = (unsigned)x0i < WW, ix1 = (unsigned)(x0i + 1) < WW;
        float m00 = (valid && iy0 && ix0) ? 1.f : 0.f;
        float m01 = (valid && iy0 && ix1) ? 1.f : 0.f;
        float m10 = (valid && iy1 && ix0) ? 1.f : 0.f;
        float m11 = (valid && iy1 && ix1) ? 1.f : 0.f;
        int yc0 = min(max(y0i, 0), HH - 1), yc1 = min(max(y0i + 1, 0), HH - 1);
        int xc0 = min(max(x0i, 0), WW - 1), xc1 = min(max(x0i + 1, 0), WW - 1);
        posI[e] = make_int4(yc0 * WW + xc0, yc0 * WW + xc1, yc1 * WW + xc0, yc1 * WW + xc1);
        posW[e] = make_float4(wy0 * wx0 * m00, wy0 * wx1 * m01, wy1 * wx0 * m10, wy1 * wx1 * m11);
    }
    __syncthreads();

    int lane  = tid & 63;
    int wave  = tid >> 6;
    int prow  = lane & 15;               // A row (pixel) within wave tile
    int khalf = lane >> 4;               // k-subchunk
    int ebase = (wave * 16 + prow) * 9;

    f32x4 acc0 = {0.f, 0.f, 0.f, 0.f};
    f32x4 acc1 = {0.f, 0.f, 0.f, 0.f};
    f32x4 acc2 = {0.f, 0.f, 0.f, 0.f};
    f32x4 acc3 = {0.f, 0.f, 0.f, 0.f};

    #pragma unroll 2
    for (int kk = 0; kk < 18; ++kk) {
        int tap = kk >> 1;
        short8 bf0 = wf[(kk * 4 + 0) * 64 + lane];
        short8 bf1 = wf[(kk * 4 + 1) * 64 + lane];
        short8 bf2 = wf[(kk * 4 + 2) * 64 + lane];
        short8 bf3 = wf[(kk * 4 + 3) * 64 + lane];
        int4   io = posI[ebase + tap];
        float4 w4 = posW[ebase + tap];
        int c0 = ((kk & 1) << 5) + (khalf << 3);
        const unsigned short* bp = pT + c0;
        ushort8 s0 = *(const ushort8*)(bp + (size_t)io.x * 64);
        ushort8 s1 = *(const ushort8*)(bp + (size_t)io.y * 64);
        ushort8 s2 = *(const ushort8*)(bp + (size_t)io.z * 64);
        ushort8 s3 = *(const ushort8*)(bp + (size_t)io.w * 64);
        short8 a;
        #pragma unroll
        for (int j = 0; j < 8; ++j) {
            float v = w4.x * bf2f(s0[j]) + w4.y * bf2f(s1[j])
                    + w4.z * bf2f(s2[j]) + w4.w * bf2f(s3[j]);
            a[j] = f2bf(v);
        }
        acc0 = __builtin_amdgcn_mfma_f32_16x16x32_bf16(a, bf0, acc0, 0, 0, 0);
        acc1 = __builtin_amdgcn_mfma_f32_16x16x32_bf16(a, bf1, acc1, 0, 0, 0);
        acc2 = __builtin_amdgcn_mfma_f32_16x16x32_bf16(a, bf2, acc2, 0, 0, 0);
        acc3 = __builtin_amdgcn_mfma_f32_16x16x32_bf16(a, bf3, acc3, 0, 0, 0);
    }
    __syncthreads();                     // pos arrays dead; reuse as trans

    // D layout: col=lane&15 (o within tile), row=(lane>>4)*4+reg (pixel within wave)
    int ocol = lane & 15;
    int pr   = wave * 16 + khalf * 4;
    #pragma unroll
    for (int r = 0; r < 4; ++r) {
        trans[(0 * 16 + ocol) * 65 + pr + r] = acc0[r];
        trans[(1 * 16 + ocol) * 65 + pr + r] = acc1[r];
        trans[(2 * 16 + ocol) * 65 + pr + r] = acc2[r];
        trans[(3 * 16 + ocol) * 65 + pr + r] = acc3[r];
    }
    __syncthreads();

    float* ob = out + ((size_t)b * COUT * HH + ho) * WW + wo0;
    for (int i = tid; i < 64 * 64; i += 256) {
        int o = i >> 6, w = i & 63;
        ob[(size_t)o * HW + w] = trans[o * 65 + w];
    }
}

extern "C" void kernel_launch(void* const* d_in, const int* in_sizes, int n_in,
                              void* d_out, int out_size, void* d_ws, size_t ws_size,
                              hipStream_t stream)
{
    const float* x    = (const float*)d_in[0];
    const float* woff = (const float*)d_in[1];
    const float* wdef = (const float*)d_in[2];
    float* out  = (float*)d_out;
    float* offs = (float*)d_ws;                                            // 9.44 MB
    unsigned short* wfrag = (unsigned short*)(offs + (size_t)BATCH * OFFC * HW);  // 73.7 KB
    unsigned short* xT    = wfrag + 36864;                                 // 16.8 MB

    hipLaunchKernelGGL(offsets_conv_k, dim3(BATCH * 64), dim3(256), 0, stream,
                       x, woff, offs);
    hipLaunchKernelGGL(to_chlast_k, dim3(BATCH * HH), dim3(256), 0, stream,
                       x, xT);
    hipLaunchKernelGGL(build_wfrag_k, dim3(COUT * 576 / 256), dim3(256), 0, stream,
                       wdef, wfrag);
    hipLaunchKernelGGL(deform_main_k, dim3(BATCH * HH * 2), dim3(256), 0, stream,
                       xT, offs, (const short8*)wfrag, out);
}

// Round 5
// 123.705 us; speedup vs baseline: 6.6795x; 2.0023x over previous
//
#include <hip/hip_runtime.h>
#include <hip/hip_bf16.h>

#define BATCH 8
#define CIN   64
#define COUT  64
#define HH    128
#define WW    128
#define HW    (HH * WW)
#define OFFC  18
#define KK    9

typedef __attribute__((ext_vector_type(8))) short short8;
typedef __attribute__((ext_vector_type(8))) unsigned short ushort8;
typedef __attribute__((ext_vector_type(4))) float f32x4;

__device__ __forceinline__ float bf2f(unsigned short u) {
    return __builtin_bit_cast(float, ((unsigned int)u) << 16);
}
__device__ __forceinline__ short f2bf(float v) {
    __hip_bfloat16 h = __float2bfloat16(v);
    return __builtin_bit_cast(short, h);
}

// ------- Kernel X: x (b,c,h,w) f32 -> xT (b,h,w,c) bf16, one (b,ho) row per block -------
__global__ __launch_bounds__(256) void to_chlast_k(
    const float* __restrict__ x, unsigned short* __restrict__ xT)
{
    __shared__ unsigned short t[128 * 72];   // [w][c], pad 72 keeps 16B-aligned ushort8 rows
    int blk = blockIdx.x;                    // b*HH + ho
    int ho = blk & (HH - 1);
    int b  = blk >> 7;
    int tid = threadIdx.x;

    const float* xr = x + (size_t)b * CIN * HW + ho * WW;
    for (int i = tid; i < 2048; i += 256) {  // c = i>>5, 4 consecutive w
        int c = i >> 5, w4 = (i & 31) * 4;
        float4 v = *(const float4*)(xr + (size_t)c * HW + w4);
        t[(w4 + 0) * 72 + c] = (unsigned short)f2bf(v.x);
        t[(w4 + 1) * 72 + c] = (unsigned short)f2bf(v.y);
        t[(w4 + 2) * 72 + c] = (unsigned short)f2bf(v.z);
        t[(w4 + 3) * 72 + c] = (unsigned short)f2bf(v.w);
    }
    __syncthreads();

    unsigned short* orow = xT + (size_t)blk * WW * 64;
    for (int j = tid; j < 1024; j += 256) {  // w = j>>3, 8 channels
        int w = j >> 3, c8 = (j & 7) * 8;
        *(ushort8*)(orow + w * 64 + c8) = *(const ushort8*)(t + w * 72 + c8);
    }
}

// ------- Kernel B: w_deform (o,c,kh,kw) -> bf16 B-fragments wf[kk][nt(4)][lane][8] -------
// B[k=kk*32+(lane>>4)*8+j][col=lane&15] = w[o=nt*16+col][ck=k], ck = tap*64+c
__global__ __launch_bounds__(256) void build_wfrag_k(
    const float* __restrict__ wd, unsigned short* __restrict__ wf)
{
    int idx = blockIdx.x * 256 + threadIdx.x;   // o*576 + ck, 36864 total
    int ck = idx % 576;
    int o  = idx / 576;
    int c = ck & 63, k = ck >> 6;
    float v = wd[o * 576 + c * 9 + k];
    int kk = ck >> 5, nt = o >> 4;
    int lane = (o & 15) | (((ck >> 3) & 3) << 4);
    int j = ck & 7;
    wf[((kk * 4 + nt) * 64 + lane) * 8 + j] = (unsigned short)f2bf(v);
}

// ------- Kernel B2: w_offset (18,64,3,3) -> bf16 B-fragments wfo[kk][nt(2)][lane][8] -------
// N padded 18->32 with zero columns; K = tap*64 + c.
__global__ __launch_bounds__(256) void build_wfo_k(
    const float* __restrict__ wo, unsigned short* __restrict__ wfo)
{
    int idx = blockIdx.x * 256 + threadIdx.x;   // ov*576 + ck, ov = 0..31 (virtual oc)
    if (idx >= 32 * 576) return;
    int ck = idx % 576;
    int ov = idx / 576;
    int c = ck & 63, tap = ck >> 6;
    float v = (ov < OFFC) ? wo[ov * 576 + c * 9 + tap] : 0.f;
    int kk = ck >> 5, nt = ov >> 4;
    int lane = (ov & 15) | (((ck >> 3) & 3) << 4);
    int j = ck & 7;
    wfo[((kk * 2 + nt) * 64 + lane) * 8 + j] = (unsigned short)f2bf(v);
}

// ---------------- Kernel C: fused offsets-conv + gather + deform MFMA ----------------
// Block = 64 pixels (half-row) x 64 outputs, 4 waves x 16 pixels.
// Phase A: offsets conv (N=18 pad 32) via MFMA from channels-last xT -> offsL in LDS.
// Phase 0: positions + pre-masked bilinear weights from offsL.
// Phase 1: gather-to-A-fragment (4 corners x ushort8) + 4 MFMAs per K-step.
// Grid blk = (ho*2+wseg)*8 + b: round-robin blk%8 -> each XCD owns one batch,
// per-XCD working set ~2.1MB xT fits the 4MB XCD L2.
__global__ __launch_bounds__(256) void deform_fused_k(
    const unsigned short* __restrict__ xT,
    const short8* __restrict__ wfo,
    const short8* __restrict__ wf, float* __restrict__ out)
{
    __shared__ alignas(16) char smem[23552];
    float*  offsL = (float*)smem;                     // [64][20] = 5120 B
    int4*   posI  = (int4*)(smem + 5120);             // 576*16 = 9216 B
    float4* posW  = (float4*)(smem + 5120 + 9216);    // 576*16 = 9216 B
    float*  trans = (float*)(smem + 5120);            // aliases posI/posW after K-loop

    int tid  = threadIdx.x;
    int blk  = blockIdx.x;               // (ho*2+wseg)*8 + b
    int b    = blk & 7;
    int t    = blk >> 3;
    int wseg = t & 1;
    int ho   = t >> 1;
    int wo0  = wseg * 64;

    const unsigned short* pT = xT + (size_t)b * HW * 64;

    int lane  = tid & 63;
    int wave  = tid >> 6;
    int prow  = lane & 15;               // pixel within wave tile
    int khalf = lane >> 4;               // k-subchunk

    // ---- phase A: offsets = conv3x3(x, w_offset) via MFMA, results to offsL ----
    {
        int wo = wo0 + wave * 16 + prow;
        f32x4 oa0 = {0.f, 0.f, 0.f, 0.f};
        f32x4 oa1 = {0.f, 0.f, 0.f, 0.f};
        #pragma unroll
        for (int kk = 0; kk < 18; ++kk) {
            int tap = kk >> 1;
            int y  = ho + tap / 3 - 1;
            int xw = wo + tap % 3 - 1;
            int c0 = ((kk & 1) << 5) + (khalf << 3);
            short8 a = {0, 0, 0, 0, 0, 0, 0, 0};
            if ((unsigned)y < HH && (unsigned)xw < WW)
                a = *(const short8*)(pT + (((size_t)(y * WW + xw)) << 6) + c0);
            short8 b0 = wfo[(kk * 2 + 0) * 64 + lane];
            short8 b1 = wfo[(kk * 2 + 1) * 64 + lane];
            oa0 = __builtin_amdgcn_mfma_f32_16x16x32_bf16(a, b0, oa0, 0, 0, 0);
            oa1 = __builtin_amdgcn_mfma_f32_16x16x32_bf16(a, b1, oa1, 0, 0, 0);
        }
        int ocol = lane & 15;
        int pix0 = wave * 16 + khalf * 4;
        #pragma unroll
        for (int r = 0; r < 4; ++r)
            offsL[(pix0 + r) * 20 + ocol] = oa0[r];
        if (ocol < 2) {
            #pragma unroll
            for (int r = 0; r < 4; ++r)
                offsL[(pix0 + r) * 20 + 16 + ocol] = oa1[r];
        }
    }
    __syncthreads();

    // ---- phase 0: 64 pixels x 9 taps -> clamped corner indices + pre-masked weights ----
    for (int e = tid; e < 576; e += 256) {
        int p = e / 9, k = e - p * 9;
        int wo = wo0 + p;
        float dy = offsL[p * 20 + 2 * k];
        float dx = offsL[p * 20 + 2 * k + 1];
        float yy = (float)(ho - 1 + k / 3) + dy;
        float xx = (float)(wo - 1 + k % 3) + dx;
        float y0 = floorf(yy), x0 = floorf(xx);
        float wy1 = yy - y0, wx1 = xx - x0;
        float wy0 = 1.f - wy1, wx0 = 1.f - wx1;
        bool valid = (yy > -1.f) && (yy < (float)HH) && (xx > -1.f) && (xx < (float)WW);
        int y0i = (int)y0, x0i = (int)x0;
        bool iy0 = (unsigned)y0i < HH, iy1 = (unsigned)(y0i + 1) < HH;
        bool ix0 = (unsigned)x0i < WW, ix1 = (unsigned)(x0i + 1) < WW;
        float m00 = (valid && iy0 && ix0) ? 1.f : 0.f;
        float m01 = (valid && iy0 && ix1) ? 1.f : 0.f;
        float m10 = (valid && iy1 && ix0) ? 1.f : 0.f;
        float m11 = (valid && iy1 && ix1) ? 1.f : 0.f;
        int yc0 = min(max(y0i, 0), HH - 1), yc1 = min(max(y0i + 1, 0), HH - 1);
        int xc0 = min(max(x0i, 0), WW - 1), xc1 = min(max(x0i + 1, 0), WW - 1);
        posI[e] = make_int4(yc0 * WW + xc0, yc0 * WW + xc1, yc1 * WW + xc0, yc1 * WW + xc1);
        posW[e] = make_float4(wy0 * wx0 * m00, wy0 * wx1 * m01, wy1 * wx0 * m10, wy1 * wx1 * m11);
    }
    __syncthreads();

    // ---- phase 1: gather + MFMA ----
    int ebase = (wave * 16 + prow) * 9;

    f32x4 acc0 = {0.f, 0.f, 0.f, 0.f};
    f32x4 acc1 = {0.f, 0.f, 0.f, 0.f};
    f32x4 acc2 = {0.f, 0.f, 0.f, 0.f};
    f32x4 acc3 = {0.f, 0.f, 0.f, 0.f};

    #pragma unroll 2
    for (int kk = 0; kk < 18; ++kk) {
        int tap = kk >> 1;
        short8 bf0 = wf[(kk * 4 + 0) * 64 + lane];
        short8 bf1 = wf[(kk * 4 + 1) * 64 + lane];
        short8 bf2 = wf[(kk * 4 + 2) * 64 + lane];
        short8 bf3 = wf[(kk * 4 + 3) * 64 + lane];
        int4   io = posI[ebase + tap];
        float4 w4 = posW[ebase + tap];
        int c0 = ((kk & 1) << 5) + (khalf << 3);
        const unsigned short* bp = pT + c0;
        ushort8 s0 = *(const ushort8*)(bp + (size_t)io.x * 64);
        ushort8 s1 = *(const ushort8*)(bp + (size_t)io.y * 64);
        ushort8 s2 = *(const ushort8*)(bp + (size_t)io.z * 64);
        ushort8 s3 = *(const ushort8*)(bp + (size_t)io.w * 64);
        short8 a;
        #pragma unroll
        for (int j = 0; j < 8; ++j) {
            float v = w4.x * bf2f(s0[j]) + w4.y * bf2f(s1[j])
                    + w4.z * bf2f(s2[j]) + w4.w * bf2f(s3[j]);
            a[j] = f2bf(v);
        }
        acc0 = __builtin_amdgcn_mfma_f32_16x16x32_bf16(a, bf0, acc0, 0, 0, 0);
        acc1 = __builtin_amdgcn_mfma_f32_16x16x32_bf16(a, bf1, acc1, 0, 0, 0);
        acc2 = __builtin_amdgcn_mfma_f32_16x16x32_bf16(a, bf2, acc2, 0, 0, 0);
        acc3 = __builtin_amdgcn_mfma_f32_16x16x32_bf16(a, bf3, acc3, 0, 0, 0);
    }
    __syncthreads();                     // pos arrays dead; reuse as trans

    // D layout: col=lane&15 (o within tile), row=(lane>>4)*4+reg (pixel within wave)
    int ocol = lane & 15;
    int pr   = wave * 16 + khalf * 4;
    #pragma unroll
    for (int r = 0; r < 4; ++r) {
        trans[(0 * 16 + ocol) * 65 + pr + r] = acc0[r];
        trans[(1 * 16 + ocol) * 65 + pr + r] = acc1[r];
        trans[(2 * 16 + ocol) * 65 + pr + r] = acc2[r];
        trans[(3 * 16 + ocol) * 65 + pr + r] = acc3[r];
    }
    __syncthreads();

    float* ob = out + ((size_t)b * COUT * HH + ho) * WW + wo0;
    for (int i = tid; i < 64 * 64; i += 256) {
        int o = i >> 6, w = i & 63;
        ob[(size_t)o * HW + w] = trans[o * 65 + w];
    }
}

extern "C" void kernel_launch(void* const* d_in, const int* in_sizes, int n_in,
                              void* d_out, int out_size, void* d_ws, size_t ws_size,
                              hipStream_t stream)
{
    const float* x    = (const float*)d_in[0];
    const float* woff = (const float*)d_in[1];
    const float* wdef = (const float*)d_in[2];
    float* out  = (float*)d_out;

    unsigned short* wfrag = (unsigned short*)d_ws;          // 36864 ush = 73.7 KB
    unsigned short* wfo   = wfrag + 36864;                  // 18432 ush = 36.9 KB
    unsigned short* xT    = wfo + 18432;                    // 8*16384*64 ush = 16.8 MB

    hipLaunchKernelGGL(to_chlast_k, dim3(BATCH * HH), dim3(256), 0, stream,
                       x, xT);
    hipLaunchKernelGGL(build_wfrag_k, dim3(COUT * 576 / 256), dim3(256), 0, stream,
                       wdef, wfrag);
    hipLaunchKernelGGL(build_wfo_k, dim3(32 * 576 / 256), dim3(256), 0, stream,
                       woff, wfo);
    hipLaunchKernelGGL(deform_fused_k, dim3(BATCH * HH * 2), dim3(256), 0, stream,
                       xT, (const short8*)wfo, (const short8*)wfrag, out);
}